// Round 1
// baseline (91.333 us; speedup 1.0000x reference)
//
#include <hip/hip_runtime.h>
#include <stdint.h>

#define LOG2E 1.4426950408889634f

typedef __attribute__((ext_vector_type(8))) short bf16x8;
typedef __attribute__((ext_vector_type(4))) float f32x4;

__device__ __forceinline__ unsigned short f2bf(float f) {
  union { float f; unsigned int u; } v; v.f = f;
  unsigned int u = v.u;
  u += 0x7FFFu + ((u >> 16) & 1u);   // round-to-nearest-even
  return (unsigned short)(u >> 16);
}

// ---------- kernel: f32 -> bf16 convert ----------
__global__ void cvt_f32_bf16(const float* __restrict__ src, unsigned short* __restrict__ dst, int n4) {
  int i = blockIdx.x * blockDim.x + threadIdx.x;
  if (i < n4) {
    float4 v = reinterpret_cast<const float4*>(src)[i];
    ushort4 o;
    o.x = f2bf(v.x); o.y = f2bf(v.y); o.z = f2bf(v.z); o.w = f2bf(v.w);
    reinterpret_cast<ushort4*>(dst)[i] = o;
  }
}

// ---------- kernel: transpose 256x256 f32 -> bf16 (weights, k-fast for B-frags) ----------
struct WPtrs { const float* src[4]; unsigned short* dst[4]; };
__global__ void transpose_w(WPtrs p) {
  __shared__ float tile[32][33];
  const float* src = p.src[blockIdx.z];
  unsigned short* dst = p.dst[blockIdx.z];
  int x = blockIdx.x * 32 + threadIdx.x;
  int y = blockIdx.y * 32 + threadIdx.y;
  #pragma unroll
  for (int j = 0; j < 32; j += 8)
    tile[threadIdx.y + j][threadIdx.x] = src[(y + j) * 256 + x];
  __syncthreads();
  int xo = blockIdx.y * 32 + threadIdx.x;
  int yo = blockIdx.x * 32 + threadIdx.y;
  #pragma unroll
  for (int j = 0; j < 32; j += 8)
    dst[(yo + j) * 256 + xo] = f2bf(tile[threadIdx.x][threadIdx.y + j]);
}

// ---------- GEMM: [16384,256] x [256,128-tile], bf16 MFMA, fp32 accum ----------
// MODE 0: QKV (grid.y = 6: wsel = y>>1, n-half = y&1). q,k -> [B,T,256]; v -> transposed [B,H,D,T].
// MODE 1: out-proj (grid.y = 2), adds bias, writes f32.
template<int MODE>
__launch_bounds__(256, 2)
__global__ void gemm128(const unsigned short* __restrict__ A,
                        const unsigned short* __restrict__ Wt,   // transposed weights [n][k]
                        unsigned short* __restrict__ q_out,
                        unsigned short* __restrict__ k_out,
                        unsigned short* __restrict__ vT,
                        const float* __restrict__ bo,
                        float* __restrict__ f_out) {
  __shared__ unsigned short As[128][72];   // +8 pad: 144B stride, bank stride 4 -> 2-way (free)
  __shared__ unsigned short Bs[128][72];
  const int tid = threadIdx.x;
  const int m0 = blockIdx.x * 128;
  int wsel, n0;
  if (MODE == 0) { wsel = blockIdx.y >> 1; n0 = (blockIdx.y & 1) * 128; }
  else           { wsel = 0;               n0 = blockIdx.y * 128; }
  const unsigned short* W = Wt + wsel * 65536;
  const int w = tid >> 6, lane = tid & 63;
  const int wm = (w >> 1) * 64, wn = (w & 1) * 64;
  const int lr = lane & 15, lg = lane >> 4;

  f32x4 acc[4][4] = {};

  for (int kt = 0; kt < 4; ++kt) {
    #pragma unroll
    for (int cc = 0; cc < 4; ++cc) {
      int c = tid + cc * 256;              // 1024 chunks of 8 bf16
      int row = c >> 3, col = (c & 7) * 8;
      *reinterpret_cast<int4*>(&As[row][col]) =
        *reinterpret_cast<const int4*>(&A[(size_t)(m0 + row) * 256 + kt * 64 + col]);
      *reinterpret_cast<int4*>(&Bs[row][col]) =
        *reinterpret_cast<const int4*>(&W[(size_t)(n0 + row) * 256 + kt * 64 + col]);
    }
    __syncthreads();
    #pragma unroll
    for (int kk = 0; kk < 2; ++kk) {
      bf16x8 af[4], bfr[4];
      #pragma unroll
      for (int mf = 0; mf < 4; ++mf)
        af[mf] = *reinterpret_cast<const bf16x8*>(&As[wm + mf * 16 + lr][kk * 32 + lg * 8]);
      #pragma unroll
      for (int nf = 0; nf < 4; ++nf)
        bfr[nf] = *reinterpret_cast<const bf16x8*>(&Bs[wn + nf * 16 + lr][kk * 32 + lg * 8]);
      #pragma unroll
      for (int mf = 0; mf < 4; ++mf)
        #pragma unroll
        for (int nf = 0; nf < 4; ++nf)
          acc[mf][nf] = __builtin_amdgcn_mfma_f32_16x16x32_bf16(af[mf], bfr[nf], acc[mf][nf], 0, 0, 0);
    }
    __syncthreads();
  }

  if (MODE == 0) {
    if (wsel < 2) {
      unsigned short* dst = (wsel == 0) ? q_out : k_out;
      #pragma unroll
      for (int mf = 0; mf < 4; ++mf)
        #pragma unroll
        for (int nf = 0; nf < 4; ++nf)
          #pragma unroll
          for (int r = 0; r < 4; ++r)
            dst[(size_t)(m0 + wm + mf * 16 + lg * 4 + r) * 256 + (n0 + wn + nf * 16 + lr)] =
              f2bf(acc[mf][nf][r]);
    } else {
      #pragma unroll
      for (int mf = 0; mf < 4; ++mf)
        #pragma unroll
        for (int nf = 0; nf < 4; ++nf) {
          int ncol = n0 + wn + nf * 16 + lr;
          int h = ncol >> 5, d = ncol & 31;
          int m = m0 + wm + mf * 16 + lg * 4;
          int b = m >> 9, t = m & 511;
          ushort4 pk;
          pk.x = f2bf(acc[mf][nf][0]); pk.y = f2bf(acc[mf][nf][1]);
          pk.z = f2bf(acc[mf][nf][2]); pk.w = f2bf(acc[mf][nf][3]);
          *reinterpret_cast<ushort4*>(&vT[((size_t)((b * 8 + h) * 32 + d)) * 512 + t]) = pk;
        }
    }
  } else {
    #pragma unroll
    for (int mf = 0; mf < 4; ++mf)
      #pragma unroll
      for (int nf = 0; nf < 4; ++nf)
        #pragma unroll
        for (int r = 0; r < 4; ++r) {
          int ncol = n0 + wn + nf * 16 + lr;
          f_out[(size_t)(m0 + wm + mf * 16 + lg * 4 + r) * 256 + ncol] = acc[mf][nf][r] + bo[ncol];
        }
  }
}

// ---------- fused causal attention with ALiBi, flash-style ----------
// grid (8 q-chunks of 64, H, B), 256 threads = 4 waves x 16 q-rows.
__launch_bounds__(256, 2)
__global__ void attn_k(const unsigned short* __restrict__ qb,
                       const unsigned short* __restrict__ kb,
                       const unsigned short* __restrict__ vT,
                       unsigned short* __restrict__ ob) {
  __shared__ unsigned short Ks[128][40];       // [k][d], pad: 80B stride (16B-aligned)
  __shared__ unsigned short Vs[32][136];       // [d][k] (v pre-transposed), 272B stride
  __shared__ unsigned short Ps[4][16][136];    // per-wave P tile [q][k]
  const int b = blockIdx.z, h = blockIdx.y, qc = blockIdx.x;
  const int q0 = qc * 64;
  const int tid = threadIdx.x, w = tid >> 6, lane = tid & 63;
  const int lr = lane & 15, lg = lane >> 4;
  const int qw = q0 + w * 16;
  const float scale = 0.17677669529663687f;    // 1/sqrt(32)
  const float slope = exp2f(-(float)(h + 1));  // ALiBi slopes for H=8: 2^-(h+1)

  // Q fragment stays in registers: A-frag row = lane&15, d = 8*(lane>>4)+j
  bf16x8 qf = *reinterpret_cast<const bf16x8*>(
      &qb[(size_t)(b * 512 + qw + lr) * 256 + h * 32 + lg * 8]);

  float m_r[4], l_r[4];
  f32x4 oacc[2] = {};
  #pragma unroll
  for (int r = 0; r < 4; ++r) { m_r[r] = -1e30f; l_r[r] = 0.f; }

  const int nt = (q0 + 191) >> 7;              // tiles of 128 k covering k <= q0+63
  for (int t = 0; t < nt; ++t) {
    const int kbase = t << 7;
    // stage K [128][32]
    #pragma unroll
    for (int cc = 0; cc < 2; ++cc) {
      int c = tid + cc * 256;
      int row = c >> 2, g = c & 3;
      *reinterpret_cast<int4*>(&Ks[row][g * 8]) =
        *reinterpret_cast<const int4*>(&kb[(size_t)(b * 512 + kbase + row) * 256 + h * 32 + g * 8]);
    }
    // stage V^T [32][128] from [B,H,D,T]
    #pragma unroll
    for (int cc = 0; cc < 2; ++cc) {
      int c = tid + cc * 256;
      int d = c >> 4, g = c & 15;
      *reinterpret_cast<int4*>(&Vs[d][g * 8]) =
        *reinterpret_cast<const int4*>(&vT[((size_t)(b * 8 + h) * 32 + d) * 512 + kbase + g * 8]);
    }
    __syncthreads();

    // S = Q K^T  (S[m=q_local, n=k_local]); logits + ALiBi + causal in fp32
    float sreg[8][4];
    #pragma unroll
    for (int kt = 0; kt < 8; ++kt) {
      bf16x8 kf = *reinterpret_cast<const bf16x8*>(&Ks[kt * 16 + lr][lg * 8]);
      f32x4 z = {};
      f32x4 s = __builtin_amdgcn_mfma_f32_16x16x32_bf16(qf, kf, z, 0, 0, 0);
      int kcol = kbase + kt * 16 + lr;
      #pragma unroll
      for (int r = 0; r < 4; ++r) {
        int qrow = qw + lg * 4 + r;
        float bias = slope * (float)(kcol - qrow);
        sreg[kt][r] = (kcol <= qrow) ? (s[r] * scale + bias) : -1e30f;
      }
    }

    // online softmax: per q-row reduce over 8 regs + 16 lanes (k within tile)
    float alpha[4];
    #pragma unroll
    for (int r = 0; r < 4; ++r) {
      float mx = sreg[0][r];
      #pragma unroll
      for (int kt = 1; kt < 8; ++kt) mx = fmaxf(mx, sreg[kt][r]);
      #pragma unroll
      for (int off = 1; off < 16; off <<= 1) mx = fmaxf(mx, __shfl_xor(mx, off));
      float mn = fmaxf(m_r[r], mx);
      alpha[r] = exp2f((m_r[r] - mn) * LOG2E);
      m_r[r] = mn;
      float rs = 0.f;
      #pragma unroll
      for (int kt = 0; kt < 8; ++kt) {
        float p = exp2f((sreg[kt][r] - mn) * LOG2E);
        sreg[kt][r] = p;
        rs += p;
      }
      #pragma unroll
      for (int off = 1; off < 16; off <<= 1) rs += __shfl_xor(rs, off);
      l_r[r] = l_r[r] * alpha[r] + rs;
      oacc[0][r] *= alpha[r];
      oacc[1][r] *= alpha[r];
    }

    // P -> LDS (re-layout for PV A-fragment)
    #pragma unroll
    for (int kt = 0; kt < 8; ++kt)
      #pragma unroll
      for (int r = 0; r < 4; ++r)
        Ps[w][lg * 4 + r][kt * 16 + lr] = f2bf(sreg[kt][r]);
    __syncthreads();

    // O += P V : A = P[16q,32k] from Ps, B = V[32k,16d] from Vs (k-fast)
    #pragma unroll
    for (int ks = 0; ks < 4; ++ks) {
      bf16x8 pa = *reinterpret_cast<const bf16x8*>(&Ps[w][lr][ks * 32 + lg * 8]);
      #pragma unroll
      for (int nf = 0; nf < 2; ++nf) {
        bf16x8 vb = *reinterpret_cast<const bf16x8*>(&Vs[nf * 16 + lr][ks * 32 + lg * 8]);
        oacc[nf] = __builtin_amdgcn_mfma_f32_16x16x32_bf16(pa, vb, oacc[nf], 0, 0, 0);
      }
    }
    __syncthreads();
  }

  #pragma unroll
  for (int r = 0; r < 4; ++r) {
    float inv = 1.0f / l_r[r];
    int qrow = qw + lg * 4 + r;
    #pragma unroll
    for (int nf = 0; nf < 2; ++nf)
      ob[(size_t)(b * 512 + qrow) * 256 + h * 32 + nf * 16 + lr] = f2bf(oacc[nf][r] * inv);
  }
}

extern "C" void kernel_launch(void* const* d_in, const int* in_sizes, int n_in,
                              void* d_out, int out_size, void* d_ws, size_t ws_size,
                              hipStream_t stream) {
  const float* x  = (const float*)d_in[0];
  const float* Wq = (const float*)d_in[1];
  const float* Wk = (const float*)d_in[2];
  const float* Wv = (const float*)d_in[3];
  const float* Wo = (const float*)d_in[4];
  const float* bo = (const float*)d_in[5];
  float* out = (float*)d_out;

  char* ws = (char*)d_ws;
  unsigned short* xb = (unsigned short*)(ws);                    // 8 MB (reused for o after QKV)
  unsigned short* qb = (unsigned short*)(ws + (8u  << 20));      // 8 MB
  unsigned short* kb = (unsigned short*)(ws + (16u << 20));      // 8 MB
  unsigned short* vT = (unsigned short*)(ws + (24u << 20));      // 8 MB
  unsigned short* wt = (unsigned short*)(ws + (32u << 20));      // 4 x 128 KB transposed weights
  unsigned short* ob = xb;                                       // reuse x-bf16 buffer

  cvt_f32_bf16<<<4096, 256, 0, stream>>>(x, xb, 1048576);

  WPtrs p;
  p.src[0] = Wq; p.src[1] = Wk; p.src[2] = Wv; p.src[3] = Wo;
  p.dst[0] = wt; p.dst[1] = wt + 65536; p.dst[2] = wt + 2 * 65536; p.dst[3] = wt + 3 * 65536;
  transpose_w<<<dim3(8, 8, 4), dim3(32, 8), 0, stream>>>(p);

  gemm128<0><<<dim3(128, 6), 256, 0, stream>>>(xb, wt, qb, kb, vT, nullptr, nullptr);
  attn_k<<<dim3(8, 8, 32), 256, 0, stream>>>(qb, kb, vT, ob);
  gemm128<1><<<dim3(128, 2), 256, 0, stream>>>(ob, wt + 3 * 65536, nullptr, nullptr, nullptr, bo, out);
}

// Round 2
// 63.643 us; speedup vs baseline: 1.4351x; 1.4351x over previous
//
#include <hip/hip_runtime.h>
#include <stdint.h>

#define LOG2E 1.4426950408889634f

typedef __attribute__((ext_vector_type(8))) short bf16x8;
typedef __attribute__((ext_vector_type(4))) float f32x4;

__device__ __forceinline__ unsigned short f2bf(float f) {
  union { float f; unsigned int u; } v; v.f = f;
  unsigned int u = v.u;
  u += 0x7FFFu + ((u >> 16) & 1u);   // round-to-nearest-even
  return (unsigned short)(u >> 16);
}

__device__ __forceinline__ unsigned int cvt_pk_bf16(float lo, float hi) {
  unsigned int r;
  asm("v_cvt_pk_bf16_f32 %0, %1, %2" : "=v"(r) : "v"(lo), "v"(hi));
  return r;
}

// ---------- kernel: f32 -> bf16 convert ----------
__global__ void cvt_f32_bf16(const float* __restrict__ src, unsigned short* __restrict__ dst, int n4) {
  int i = blockIdx.x * blockDim.x + threadIdx.x;
  if (i < n4) {
    float4 v = reinterpret_cast<const float4*>(src)[i];
    ushort4 o;
    o.x = f2bf(v.x); o.y = f2bf(v.y); o.z = f2bf(v.z); o.w = f2bf(v.w);
    reinterpret_cast<ushort4*>(dst)[i] = o;
  }
}

// ---------- kernel: transpose 256x256 f32 -> bf16 (weights, k-fast for B-frags) ----------
struct WPtrs { const float* src[4]; unsigned short* dst[4]; };
__global__ void transpose_w(WPtrs p) {
  __shared__ float tile[32][33];
  const float* src = p.src[blockIdx.z];
  unsigned short* dst = p.dst[blockIdx.z];
  int x = blockIdx.x * 32 + threadIdx.x;
  int y = blockIdx.y * 32 + threadIdx.y;
  #pragma unroll
  for (int j = 0; j < 32; j += 8)
    tile[threadIdx.y + j][threadIdx.x] = src[(y + j) * 256 + x];
  __syncthreads();
  int xo = blockIdx.y * 32 + threadIdx.x;
  int yo = blockIdx.x * 32 + threadIdx.y;
  #pragma unroll
  for (int j = 0; j < 32; j += 8)
    dst[(yo + j) * 256 + xo] = f2bf(tile[threadIdx.x][threadIdx.y + j]);
}

// ---------- GEMM: [16384,256] x [256,128-tile], bf16 MFMA, fp32 accum ----------
// MODE 0: QKV (grid.y = 6: wsel = y>>1, n-half = y&1). q,k -> [B,T,256]; v -> transposed [B,H,D,T].
// MODE 1: out-proj (grid.y = 2), adds bias, writes f32.
template<int MODE>
__launch_bounds__(256, 2)
__global__ void gemm128(const unsigned short* __restrict__ A,
                        const unsigned short* __restrict__ Wt,   // transposed weights [n][k]
                        unsigned short* __restrict__ q_out,
                        unsigned short* __restrict__ k_out,
                        unsigned short* __restrict__ vT,
                        const float* __restrict__ bo,
                        float* __restrict__ f_out) {
  __shared__ unsigned short As[128][72];   // +8 pad
  __shared__ unsigned short Bs[128][72];
  const int tid = threadIdx.x;
  const int m0 = blockIdx.x * 128;
  int wsel, n0;
  if (MODE == 0) { wsel = blockIdx.y >> 1; n0 = (blockIdx.y & 1) * 128; }
  else           { wsel = 0;               n0 = blockIdx.y * 128; }
  const unsigned short* W = Wt + wsel * 65536;
  const int w = tid >> 6, lane = tid & 63;
  const int wm = (w >> 1) * 64, wn = (w & 1) * 64;
  const int lr = lane & 15, lg = lane >> 4;

  f32x4 acc[4][4] = {};

  for (int kt = 0; kt < 4; ++kt) {
    #pragma unroll
    for (int cc = 0; cc < 4; ++cc) {
      int c = tid + cc * 256;              // 1024 chunks of 8 bf16
      int row = c >> 3, col = (c & 7) * 8;
      *reinterpret_cast<int4*>(&As[row][col]) =
        *reinterpret_cast<const int4*>(&A[(size_t)(m0 + row) * 256 + kt * 64 + col]);
      *reinterpret_cast<int4*>(&Bs[row][col]) =
        *reinterpret_cast<const int4*>(&W[(size_t)(n0 + row) * 256 + kt * 64 + col]);
    }
    __syncthreads();
    #pragma unroll
    for (int kk = 0; kk < 2; ++kk) {
      bf16x8 af[4], bfr[4];
      #pragma unroll
      for (int mf = 0; mf < 4; ++mf)
        af[mf] = *reinterpret_cast<const bf16x8*>(&As[wm + mf * 16 + lr][kk * 32 + lg * 8]);
      #pragma unroll
      for (int nf = 0; nf < 4; ++nf)
        bfr[nf] = *reinterpret_cast<const bf16x8*>(&Bs[wn + nf * 16 + lr][kk * 32 + lg * 8]);
      #pragma unroll
      for (int mf = 0; mf < 4; ++mf)
        #pragma unroll
        for (int nf = 0; nf < 4; ++nf)
          acc[mf][nf] = __builtin_amdgcn_mfma_f32_16x16x32_bf16(af[mf], bfr[nf], acc[mf][nf], 0, 0, 0);
    }
    __syncthreads();
  }

  if (MODE == 0) {
    if (wsel < 2) {
      unsigned short* dst = (wsel == 0) ? q_out : k_out;
      #pragma unroll
      for (int mf = 0; mf < 4; ++mf)
        #pragma unroll
        for (int nf = 0; nf < 4; ++nf)
          #pragma unroll
          for (int r = 0; r < 4; ++r)
            dst[(size_t)(m0 + wm + mf * 16 + lg * 4 + r) * 256 + (n0 + wn + nf * 16 + lr)] =
              f2bf(acc[mf][nf][r]);
    } else {
      #pragma unroll
      for (int mf = 0; mf < 4; ++mf)
        #pragma unroll
        for (int nf = 0; nf < 4; ++nf) {
          int ncol = n0 + wn + nf * 16 + lr;
          int h = ncol >> 5, d = ncol & 31;
          int m = m0 + wm + mf * 16 + lg * 4;
          int b = m >> 9, t = m & 511;
          ushort4 pk;
          pk.x = f2bf(acc[mf][nf][0]); pk.y = f2bf(acc[mf][nf][1]);
          pk.z = f2bf(acc[mf][nf][2]); pk.w = f2bf(acc[mf][nf][3]);
          *reinterpret_cast<ushort4*>(&vT[((size_t)((b * 8 + h) * 32 + d)) * 512 + t]) = pk;
        }
    }
  } else {
    #pragma unroll
    for (int mf = 0; mf < 4; ++mf)
      #pragma unroll
      for (int nf = 0; nf < 4; ++nf)
        #pragma unroll
        for (int r = 0; r < 4; ++r) {
          int ncol = n0 + wn + nf * 16 + lr;
          f_out[(size_t)(m0 + wm + mf * 16 + lg * 4 + r) * 256 + ncol] = acc[mf][nf][r] + bo[ncol];
        }
  }
}

// ---------- fused causal attention with ALiBi ----------
// grid (2 parity, H, B), 256 threads = 4 waves. K/V for (b,h) staged ONCE in LDS,
// then barrier-free main loop. Swapped-operand MFMAs keep softmax lane-local:
//   S^T = mfma(K, Q):  col=q=lane&15, row(k) = 4*(lane>>4)+reg
//   O^T = mfma(V^T, P^T): col=q, row(d) — rescale/normalize all lane-local.
__launch_bounds__(256, 2)
__global__ void attn_k(const unsigned short* __restrict__ qb,
                       const unsigned short* __restrict__ kb,
                       const unsigned short* __restrict__ vT,
                       unsigned short* __restrict__ ob) {
  extern __shared__ unsigned short smem[];
  unsigned short* Ks = smem;            // [512][32] shorts, 32 KB
  unsigned short* Vs = smem + 16384;    // [32][512] shorts, col-swizzled, 32 KB
  unsigned short* Pl = smem + 32768;    // 4 waves x 16 rows x 128 B, swizzled, 8 KB
  const int p = blockIdx.x, h = blockIdx.y, b = blockIdx.z;
  const int tid = threadIdx.x, wv = tid >> 6, lane = tid & 63;
  const int lr = lane & 15, lg = lane >> 4;

  // ---- stage K rows [t][d] and V^T rows [d][t] (swizzled) ----
  {
    const unsigned short* ksrc = kb + ((size_t)b * 512) * 256 + h * 32;
    #pragma unroll
    for (int it = 0; it < 8; ++it) {
      int idx = tid + it * 256;
      int row = idx >> 2, g = idx & 3;
      *reinterpret_cast<int4*>(&Ks[row * 32 + g * 8]) =
        *reinterpret_cast<const int4*>(&ksrc[(size_t)row * 256 + g * 8]);
    }
    const unsigned short* vsrc = vT + ((size_t)(b * 8 + h) * 32) * 512;
    #pragma unroll
    for (int it = 0; it < 8; ++it) {
      int idx = tid + it * 256;
      int d = idx >> 6, cg = idx & 63;
      int col = (cg * 8) ^ ((d & 7) << 3);          // short-index swizzle (byte bits 4..6)
      *reinterpret_cast<int4*>(&Vs[d * 512 + col]) =
        *reinterpret_cast<const int4*>(&vsrc[(size_t)d * 512 + cg * 8]);
    }
  }
  __syncthreads();

  const float scale2 = 0.17677669529663687f * LOG2E;   // 1/sqrt(32) * log2(e)
  const float slope2 = exp2f(-(float)(h + 1)) * LOG2E; // ALiBi slope in log2 domain
  float cc[16];
  #pragma unroll
  for (int t = 0; t < 4; ++t)
    #pragma unroll
    for (int r = 0; r < 4; ++r) cc[t * 4 + r] = slope2 * (float)(t * 16 + r);

  char* Plw = (char*)(Pl) + wv * 2048;                 // 16 rows x 128 B per wave
  const int swz = (lr & 7) << 4;                       // byte swizzle within 128B row

  for (int i = 0; i < 4; ++i) {
    const int c = p + 2 * (wv + 4 * i);                // q-chunk index 0..31, balanced
    const int qq = c * 16;
    bf16x8 qf = *reinterpret_cast<const bf16x8*>(
        &qb[((size_t)(b * 512 + qq + lr)) * 256 + h * 32 + lg * 8]);
    float m = -1e30f, l = 0.f;
    f32x4 oT0 = {0.f, 0.f, 0.f, 0.f}, oT1 = {0.f, 0.f, 0.f, 0.f};
    const int nsteps = c / 4 + 1;
    const int nfull = (qq >= 63) ? ((qq - 63) / 64 + 1) : 0;
    const float bb0 = slope2 * (float)(lg * 4 - lr - qq);

    for (int s = 0; s < nsteps; ++s) {
      const int kb0 = s * 64;
      // S^T: 4 MFMAs over 64 k-rows
      f32x4 sv[4];
      #pragma unroll
      for (int t = 0; t < 4; ++t) {
        bf16x8 kf = *reinterpret_cast<const bf16x8*>(&Ks[(kb0 + t * 16 + lr) * 32 + lg * 8]);
        f32x4 z = {0.f, 0.f, 0.f, 0.f};
        sv[t] = __builtin_amdgcn_mfma_f32_16x16x32_bf16(kf, qf, z, 0, 0, 0);
      }
      // logits in log2 domain: x = s*scale2 + slope2*(k - q)
      float bb = bb0 + slope2 * (float)kb0;
      float x[16];
      #pragma unroll
      for (int t = 0; t < 4; ++t)
        #pragma unroll
        for (int r = 0; r < 4; ++r)
          x[t * 4 + r] = sv[t][r] * scale2 + (bb + cc[t * 4 + r]);
      if (s >= nfull) {                                 // boundary step: causal mask
        int thr = qq + lr - kb0 - lg * 4;
        #pragma unroll
        for (int t = 0; t < 4; ++t)
          #pragma unroll
          for (int r = 0; r < 4; ++r)
            x[t * 4 + r] = ((t * 16 + r) <= thr) ? x[t * 4 + r] : -1e30f;
      }
      // online softmax: 15 fmax in-reg + 2 shfl (lanes lr, lr+16, lr+32, lr+48 share q)
      float bm = x[0];
      #pragma unroll
      for (int j = 1; j < 16; ++j) bm = fmaxf(bm, x[j]);
      bm = fmaxf(bm, __shfl_xor(bm, 16));
      bm = fmaxf(bm, __shfl_xor(bm, 32));
      float mn = fmaxf(m, bm);
      float alpha = __builtin_amdgcn_exp2f(m - mn);
      m = mn;
      l *= alpha;
      #pragma unroll
      for (int r = 0; r < 4; ++r) { oT0[r] *= alpha; oT1[r] *= alpha; }
      float ps = 0.f;
      #pragma unroll
      for (int j = 0; j < 16; ++j) { x[j] = __builtin_amdgcn_exp2f(x[j] - m); ps += x[j]; }
      l += ps;
      // pack P^T -> per-wave swizzled LDS strip (no barrier: same-wave RAW via lgkmcnt)
      #pragma unroll
      for (int t = 0; t < 4; ++t)
        #pragma unroll
        for (int pp = 0; pp < 2; ++pp) {
          unsigned int w2 = cvt_pk_bf16(x[t * 4 + 2 * pp], x[t * 4 + 2 * pp + 1]);
          int cbyte = (t * 32 + lg * 8 + pp * 4) ^ swz;
          *reinterpret_cast<unsigned int*>(Plw + lr * 128 + cbyte) = w2;
        }
      // O^T += V^T x P^T
      #pragma unroll
      for (int ks = 0; ks < 2; ++ks) {
        int cb = (ks * 64 + lg * 16) ^ swz;
        bf16x8 pb = *reinterpret_cast<const bf16x8*>(Plw + lr * 128 + cb);
        #pragma unroll
        for (int dt = 0; dt < 2; ++dt) {
          int d = dt * 16 + lr;
          int col = (kb0 + ks * 32 + lg * 8) ^ ((d & 7) << 3);
          bf16x8 vf = *reinterpret_cast<const bf16x8*>(&Vs[d * 512 + col]);
          if (dt == 0) oT0 = __builtin_amdgcn_mfma_f32_16x16x32_bf16(vf, pb, oT0, 0, 0, 0);
          else         oT1 = __builtin_amdgcn_mfma_f32_16x16x32_bf16(vf, pb, oT1, 0, 0, 0);
        }
      }
    }
    // finalize: cross-lane partial-l sum (m was kept common), normalize, store
    l += __shfl_xor(l, 16);
    l += __shfl_xor(l, 32);
    float inv = 1.0f / l;
    unsigned int w0 = cvt_pk_bf16(oT0[0] * inv, oT0[1] * inv);
    unsigned int w1 = cvt_pk_bf16(oT0[2] * inv, oT0[3] * inv);
    unsigned int w2 = cvt_pk_bf16(oT1[0] * inv, oT1[1] * inv);
    unsigned int w3 = cvt_pk_bf16(oT1[2] * inv, oT1[3] * inv);
    size_t obase = ((size_t)(b * 512 + qq + lr)) * 256 + h * 32;
    *reinterpret_cast<uint2*>(&ob[obase + lg * 4]) = make_uint2(w0, w1);
    *reinterpret_cast<uint2*>(&ob[obase + 16 + lg * 4]) = make_uint2(w2, w3);
  }
}

extern "C" void kernel_launch(void* const* d_in, const int* in_sizes, int n_in,
                              void* d_out, int out_size, void* d_ws, size_t ws_size,
                              hipStream_t stream) {
  const float* x  = (const float*)d_in[0];
  const float* Wq = (const float*)d_in[1];
  const float* Wk = (const float*)d_in[2];
  const float* Wv = (const float*)d_in[3];
  const float* Wo = (const float*)d_in[4];
  const float* bo = (const float*)d_in[5];
  float* out = (float*)d_out;

  char* ws = (char*)d_ws;
  unsigned short* xb = (unsigned short*)(ws);                    // 8 MB (reused for o after QKV)
  unsigned short* qb = (unsigned short*)(ws + (8u  << 20));      // 8 MB
  unsigned short* kb = (unsigned short*)(ws + (16u << 20));      // 8 MB
  unsigned short* vT = (unsigned short*)(ws + (24u << 20));      // 8 MB
  unsigned short* wt = (unsigned short*)(ws + (32u << 20));      // 4 x 128 KB transposed weights
  unsigned short* ob = xb;                                       // reuse x-bf16 buffer

  cvt_f32_bf16<<<4096, 256, 0, stream>>>(x, xb, 1048576);

  WPtrs p;
  p.src[0] = Wq; p.src[1] = Wk; p.src[2] = Wv; p.src[3] = Wo;
  p.dst[0] = wt; p.dst[1] = wt + 65536; p.dst[2] = wt + 2 * 65536; p.dst[3] = wt + 3 * 65536;
  transpose_w<<<dim3(8, 8, 4), dim3(32, 8), 0, stream>>>(p);

  gemm128<0><<<dim3(128, 6), 256, 0, stream>>>(xb, wt, qb, kb, vT, nullptr, nullptr);
  attn_k<<<dim3(2, 8, 32), 256, 73728, stream>>>(qb, kb, vT, ob);
  gemm128<1><<<dim3(128, 2), 256, 0, stream>>>(ob, wt + 3 * 65536, nullptr, nullptr, nullptr, bo, out);
}

// Round 4
// 58.461 us; speedup vs baseline: 1.5623x; 1.0886x over previous
//
#include <hip/hip_runtime.h>
#include <stdint.h>

#define LOG2E 1.4426950408889634f

typedef __attribute__((ext_vector_type(8))) short bf16x8;
typedef __attribute__((ext_vector_type(4))) float f32x4;

__device__ __forceinline__ unsigned short f2bf(float f) {
  union { float f; unsigned int u; } v; v.f = f;
  unsigned int u = v.u;
  u += 0x7FFFu + ((u >> 16) & 1u);   // round-to-nearest-even
  return (unsigned short)(u >> 16);
}

__device__ __forceinline__ unsigned int cvt_pk_bf16(float lo, float hi) {
  unsigned int r;
  asm("v_cvt_pk_bf16_f32 %0, %1, %2" : "=v"(r) : "v"(lo), "v"(hi));
  return r;
}

// ---------- kernel: transpose 256x256 f32 -> bf16 (weights, k-fast for B-frags) ----------
struct WPtrs { const float* src[4]; unsigned short* dst[4]; };
__global__ void transpose_w(WPtrs p) {
  __shared__ float tile[32][33];
  const float* src = p.src[blockIdx.z];
  unsigned short* dst = p.dst[blockIdx.z];
  int x = blockIdx.x * 32 + threadIdx.x;
  int y = blockIdx.y * 32 + threadIdx.y;
  #pragma unroll
  for (int j = 0; j < 32; j += 8)
    tile[threadIdx.y + j][threadIdx.x] = src[(y + j) * 256 + x];
  __syncthreads();
  int xo = blockIdx.y * 32 + threadIdx.x;
  int yo = blockIdx.x * 32 + threadIdx.y;
  #pragma unroll
  for (int j = 0; j < 32; j += 8)
    dst[(yo + j) * 256 + xo] = f2bf(tile[threadIdx.x][threadIdx.y + j]);
}

// ---------- GEMM: [16384,256] x [256,128-tile], bf16 MFMA, fp32 accum ----------
// MODE 0: A = x (f32, converted during staging). grid.y = 6: wsel = y>>1, n-half = y&1.
//         q,k -> [B,T,256]; v -> transposed [B,H,D,T].
// MODE 1: A = ob (bf16). grid.y = 2 n-halves; adds bias, writes f32.
template<int MODE>
__launch_bounds__(256, 3)
__global__ void gemm128(const float* __restrict__ Ax,
                        const unsigned short* __restrict__ Ab,
                        const unsigned short* __restrict__ Wt,   // transposed weights [n][k]
                        unsigned short* __restrict__ q_out,
                        unsigned short* __restrict__ k_out,
                        unsigned short* __restrict__ vT,
                        const float* __restrict__ bo,
                        float* __restrict__ f_out) {
  __shared__ unsigned short As[128][72];   // +8 pad
  __shared__ unsigned short Bs[128][72];
  const int tid = threadIdx.x;
  const int m0 = blockIdx.x * 128;
  int wsel, n0;
  if (MODE == 0) { wsel = blockIdx.y >> 1; n0 = (blockIdx.y & 1) * 128; }
  else           { wsel = 0;               n0 = blockIdx.y * 128; }
  const unsigned short* W = Wt + wsel * 65536;
  const int w = tid >> 6, lane = tid & 63;
  const int wm = (w >> 1) * 64, wn = (w & 1) * 64;
  const int lr = lane & 15, lg = lane >> 4;

  f32x4 acc[4][4] = {};

  for (int kt = 0; kt < 4; ++kt) {
    #pragma unroll
    for (int cc = 0; cc < 4; ++cc) {
      int c = tid + cc * 256;              // 1024 chunks of 8 cols
      int row = c >> 3, colg = c & 7;
      if constexpr (MODE == 0) {
        const float* s = &Ax[(size_t)(m0 + row) * 256 + kt * 64 + colg * 8];
        float4 f0 = *reinterpret_cast<const float4*>(s);
        float4 f1 = *reinterpret_cast<const float4*>(s + 4);
        uint4 pk;
        pk.x = cvt_pk_bf16(f0.x, f0.y); pk.y = cvt_pk_bf16(f0.z, f0.w);
        pk.z = cvt_pk_bf16(f1.x, f1.y); pk.w = cvt_pk_bf16(f1.z, f1.w);
        *reinterpret_cast<uint4*>(&As[row][colg * 8]) = pk;
      } else {
        *reinterpret_cast<int4*>(&As[row][colg * 8]) =
          *reinterpret_cast<const int4*>(&Ab[(size_t)(m0 + row) * 256 + kt * 64 + colg * 8]);
      }
      *reinterpret_cast<int4*>(&Bs[row][colg * 8]) =
        *reinterpret_cast<const int4*>(&W[(size_t)(n0 + row) * 256 + kt * 64 + colg * 8]);
    }
    __syncthreads();
    #pragma unroll
    for (int kk = 0; kk < 2; ++kk) {
      bf16x8 af[4], bfr[4];
      #pragma unroll
      for (int mf = 0; mf < 4; ++mf)
        af[mf] = *reinterpret_cast<const bf16x8*>(&As[wm + mf * 16 + lr][kk * 32 + lg * 8]);
      #pragma unroll
      for (int nf = 0; nf < 4; ++nf)
        bfr[nf] = *reinterpret_cast<const bf16x8*>(&Bs[wn + nf * 16 + lr][kk * 32 + lg * 8]);
      #pragma unroll
      for (int mf = 0; mf < 4; ++mf)
        #pragma unroll
        for (int nf = 0; nf < 4; ++nf)
          acc[mf][nf] = __builtin_amdgcn_mfma_f32_16x16x32_bf16(af[mf], bfr[nf], acc[mf][nf], 0, 0, 0);
    }
    __syncthreads();
  }

  if (MODE == 0) {
    if (wsel < 2) {
      unsigned short* dst = (wsel == 0) ? q_out : k_out;
      #pragma unroll
      for (int mf = 0; mf < 4; ++mf)
        #pragma unroll
        for (int nf = 0; nf < 4; ++nf)
          #pragma unroll
          for (int r = 0; r < 4; ++r)
            dst[(size_t)(m0 + wm + mf * 16 + lg * 4 + r) * 256 + (n0 + wn + nf * 16 + lr)] =
              f2bf(acc[mf][nf][r]);
    } else {
      #pragma unroll
      for (int mf = 0; mf < 4; ++mf)
        #pragma unroll
        for (int nf = 0; nf < 4; ++nf) {
          int ncol = n0 + wn + nf * 16 + lr;
          int h = ncol >> 5, d = ncol & 31;
          int m = m0 + wm + mf * 16 + lg * 4;
          int b = m >> 9, t = m & 511;
          ushort4 pk;
          pk.x = f2bf(acc[mf][nf][0]); pk.y = f2bf(acc[mf][nf][1]);
          pk.z = f2bf(acc[mf][nf][2]); pk.w = f2bf(acc[mf][nf][3]);
          *reinterpret_cast<ushort4*>(&vT[((size_t)((b * 8 + h) * 32 + d)) * 512 + t]) = pk;
        }
    }
  } else {
    #pragma unroll
    for (int mf = 0; mf < 4; ++mf)
      #pragma unroll
      for (int nf = 0; nf < 4; ++nf)
        #pragma unroll
        for (int r = 0; r < 4; ++r) {
          int ncol = n0 + wn + nf * 16 + lr;
          f_out[(size_t)(m0 + wm + mf * 16 + lg * 4 + r) * 256 + ncol] = acc[mf][nf][r] + bo[ncol];
        }
  }
}

// ---------- fused causal attention with ALiBi ----------
// grid (2, H, B) = 512 blocks (2/CU), 256 threads = 4 waves — R1's PROVEN launch shape,
// static 72 KB LDS. Each wave runs FOUR independent q-chunks in flight (ILP), sharing
// ONE per-wave P strip (WAR across chunks ordered by same-wave lgkmcnt, as R1's RAW).
struct CSt {
  bf16x8 qf;
  f32x4 o0, o1;
  float m, l, bb0;
  int nfull, qq;
};

__device__ __forceinline__ void attn_init(CSt& st, int c, const unsigned short* qb,
    int b, int h, int lr, int lg, float slope2) {
  st.qq = c * 16;
  st.qf = *reinterpret_cast<const bf16x8*>(
      &qb[(size_t)(b * 512 + st.qq + lr) * 256 + h * 32 + lg * 8]);
  f32x4 z = {0.f, 0.f, 0.f, 0.f};
  st.o0 = z; st.o1 = z;
  st.m = -1e30f; st.l = 0.f;
  st.nfull = (st.qq >= 63) ? ((st.qq - 63) / 64 + 1) : 0;
  st.bb0 = slope2 * (float)(lg * 4 - lr - st.qq);
}

__device__ __forceinline__ void attn_step(CSt& st, int s,
    const unsigned short* __restrict__ Ks, const unsigned short* __restrict__ Vs,
    char* __restrict__ Pw, int lr, int lg, float scale2, float slope2,
    const float* cc, int swz) {
  const int kb0 = s * 64;
  const int kchunk = (lg ^ ((lr >> 1) & 3)) * 8;     // Ks swizzled chunk position
  f32x4 sv[4];
  #pragma unroll
  for (int t = 0; t < 4; ++t) {
    bf16x8 kf = *reinterpret_cast<const bf16x8*>(&Ks[(kb0 + t * 16 + lr) * 32 + kchunk]);
    f32x4 z = {0.f, 0.f, 0.f, 0.f};
    sv[t] = __builtin_amdgcn_mfma_f32_16x16x32_bf16(kf, st.qf, z, 0, 0, 0);
  }
  float bb = st.bb0 + slope2 * (float)kb0;
  float x[16];
  #pragma unroll
  for (int t = 0; t < 4; ++t)
    #pragma unroll
    for (int r = 0; r < 4; ++r)
      x[t * 4 + r] = sv[t][r] * scale2 + (bb + cc[t * 4 + r]);
  if (s >= st.nfull) {                                // boundary step: causal mask
    int thr = st.qq + lr - kb0 - lg * 4;
    #pragma unroll
    for (int t = 0; t < 4; ++t)
      #pragma unroll
      for (int r = 0; r < 4; ++r)
        x[t * 4 + r] = ((t * 16 + r) <= thr) ? x[t * 4 + r] : -1e30f;
  }
  // online softmax (lane-local row + 2 shfl)
  float bm = x[0];
  #pragma unroll
  for (int j = 1; j < 16; ++j) bm = fmaxf(bm, x[j]);
  bm = fmaxf(bm, __shfl_xor(bm, 16));
  bm = fmaxf(bm, __shfl_xor(bm, 32));
  float mn = fmaxf(st.m, bm);
  float alpha = __builtin_amdgcn_exp2f(st.m - mn);
  st.m = mn;
  st.l *= alpha;
  #pragma unroll
  for (int r = 0; r < 4; ++r) { st.o0[r] *= alpha; st.o1[r] *= alpha; }
  float ps = 0.f;
  #pragma unroll
  for (int j = 0; j < 16; ++j) { x[j] = __builtin_amdgcn_exp2f(x[j] - mn); ps += x[j]; }
  st.l += ps;
  // pack P^T -> per-wave swizzled LDS strip (same-wave ordering via lgkmcnt)
  char* Prow = Pw + lr * 128;
  #pragma unroll
  for (int t = 0; t < 4; ++t)
    #pragma unroll
    for (int pp = 0; pp < 2; ++pp) {
      unsigned int w2 = cvt_pk_bf16(x[t * 4 + 2 * pp], x[t * 4 + 2 * pp + 1]);
      *reinterpret_cast<unsigned int*>(Prow + ((t * 32 + lg * 8 + pp * 4) ^ swz)) = w2;
    }
  // O^T += V^T x P^T
  #pragma unroll
  for (int ks = 0; ks < 2; ++ks) {
    bf16x8 pb = *reinterpret_cast<const bf16x8*>(Prow + ((ks * 64 + lg * 16) ^ swz));
    #pragma unroll
    for (int dt = 0; dt < 2; ++dt) {
      int col = (kb0 + ks * 32 + lg * 8) ^ ((lr & 7) << 3);
      bf16x8 vf = *reinterpret_cast<const bf16x8*>(&Vs[(dt * 16 + lr) * 512 + col]);
      if (dt == 0) st.o0 = __builtin_amdgcn_mfma_f32_16x16x32_bf16(vf, pb, st.o0, 0, 0, 0);
      else         st.o1 = __builtin_amdgcn_mfma_f32_16x16x32_bf16(vf, pb, st.o1, 0, 0, 0);
    }
  }
}

__device__ __forceinline__ void attn_fin(CSt& st, unsigned short* __restrict__ ob,
                                         int b, int h, int lr, int lg) {
  float l = st.l;
  l += __shfl_xor(l, 16);
  l += __shfl_xor(l, 32);
  float inv = 1.0f / l;
  unsigned int w0 = cvt_pk_bf16(st.o0[0] * inv, st.o0[1] * inv);
  unsigned int w1 = cvt_pk_bf16(st.o0[2] * inv, st.o0[3] * inv);
  unsigned int w2 = cvt_pk_bf16(st.o1[0] * inv, st.o1[1] * inv);
  unsigned int w3 = cvt_pk_bf16(st.o1[2] * inv, st.o1[3] * inv);
  size_t obase = (size_t)(b * 512 + st.qq + lr) * 256 + h * 32;
  *reinterpret_cast<uint2*>(&ob[obase + lg * 4]) = make_uint2(w0, w1);
  *reinterpret_cast<uint2*>(&ob[obase + 16 + lg * 4]) = make_uint2(w2, w3);
}

__launch_bounds__(256, 2)
__global__ void attn_k(const unsigned short* __restrict__ qb,
                       const unsigned short* __restrict__ kb,
                       const unsigned short* __restrict__ vT,
                       unsigned short* __restrict__ ob) {
  __shared__ unsigned short Ks[512 * 32];   // chunk-swizzled, 32 KB
  __shared__ unsigned short Vs[32 * 512];   // col-swizzled, 32 KB
  __shared__ char Pb[8192];                 // 4 waves x 2 KB shared P strips
  const int p = blockIdx.x, h = blockIdx.y, b = blockIdx.z;
  const int tid = threadIdx.x, wv = tid >> 6, lane = tid & 63;
  const int lr = lane & 15, lg = lane >> 4;

  // ---- stage K rows [t][d] (chunk-swizzled) and V^T rows [d][t] (swizzled) ----
  {
    const unsigned short* ksrc = kb + ((size_t)b * 512) * 256 + h * 32;
    #pragma unroll
    for (int it = 0; it < 8; ++it) {
      int idx = tid + it * 256;
      int row = idx >> 2, g = idx & 3;
      int gs = g ^ ((row >> 1) & 3);
      *reinterpret_cast<int4*>(&Ks[row * 32 + gs * 8]) =
        *reinterpret_cast<const int4*>(&ksrc[(size_t)row * 256 + g * 8]);
    }
    const unsigned short* vsrc = vT + ((size_t)(b * 8 + h) * 32) * 512;
    #pragma unroll
    for (int it = 0; it < 8; ++it) {
      int idx = tid + it * 256;
      int d = idx >> 6, cg = idx & 63;
      int col = (cg * 8) ^ ((d & 7) << 3);
      *reinterpret_cast<int4*>(&Vs[d * 512 + col]) =
        *reinterpret_cast<const int4*>(&vsrc[(size_t)d * 512 + cg * 8]);
    }
  }
  __syncthreads();

  const float scale2 = 0.17677669529663687f * LOG2E;   // 1/sqrt(32) * log2(e)
  const float slope2 = exp2f(-(float)(h + 1)) * LOG2E; // ALiBi slope, log2 domain
  float cc[16];
  #pragma unroll
  for (int t = 0; t < 4; ++t)
    #pragma unroll
    for (int r = 0; r < 4; ++r) cc[t * 4 + r] = slope2 * (float)(t * 16 + r);
  const int swz = (lr & 7) << 4;
  char* Pw = Pb + wv * 2048;

  // four balanced chunks per global wave id g = p*4 + wv, all in flight
  const int g = p * 4 + wv;
  const int c0 = g, c1 = 15 - g, c2 = 16 + g, c3 = 31 - g;
  CSt s0, s1, s2, s3;
  attn_init(s0, c0, qb, b, h, lr, lg, slope2);
  attn_init(s1, c1, qb, b, h, lr, lg, slope2);
  attn_init(s2, c2, qb, b, h, lr, lg, slope2);
  attn_init(s3, c3, qb, b, h, lr, lg, slope2);
  const int n0 = c0 / 4 + 1, n1 = c1 / 4 + 1, n2 = c2 / 4 + 1, n3 = c3 / 4 + 1;

  for (int s = 0; s < n3; ++s) {
    if (s < n0) attn_step(s0, s, Ks, Vs, Pw, lr, lg, scale2, slope2, cc, swz);
    if (s < n1) attn_step(s1, s, Ks, Vs, Pw, lr, lg, scale2, slope2, cc, swz);
    if (s < n2) attn_step(s2, s, Ks, Vs, Pw, lr, lg, scale2, slope2, cc, swz);
    attn_step(s3, s, Ks, Vs, Pw, lr, lg, scale2, slope2, cc, swz);
  }

  attn_fin(s0, ob, b, h, lr, lg);
  attn_fin(s1, ob, b, h, lr, lg);
  attn_fin(s2, ob, b, h, lr, lg);
  attn_fin(s3, ob, b, h, lr, lg);
}

extern "C" void kernel_launch(void* const* d_in, const int* in_sizes, int n_in,
                              void* d_out, int out_size, void* d_ws, size_t ws_size,
                              hipStream_t stream) {
  const float* x  = (const float*)d_in[0];
  const float* Wq = (const float*)d_in[1];
  const float* Wk = (const float*)d_in[2];
  const float* Wv = (const float*)d_in[3];
  const float* Wo = (const float*)d_in[4];
  const float* bo = (const float*)d_in[5];
  float* out = (float*)d_out;

  char* ws = (char*)d_ws;
  unsigned short* qb = (unsigned short*)(ws);                    // 8 MB
  unsigned short* kb = (unsigned short*)(ws + (8u  << 20));      // 8 MB
  unsigned short* vT = (unsigned short*)(ws + (16u << 20));      // 8 MB
  unsigned short* ob = (unsigned short*)(ws + (24u << 20));      // 8 MB
  unsigned short* wt = (unsigned short*)(ws + (32u << 20));      // 4 x 128 KB transposed weights

  WPtrs p;
  p.src[0] = Wq; p.src[1] = Wk; p.src[2] = Wv; p.src[3] = Wo;
  p.dst[0] = wt; p.dst[1] = wt + 65536; p.dst[2] = wt + 2 * 65536; p.dst[3] = wt + 3 * 65536;
  transpose_w<<<dim3(8, 8, 4), dim3(32, 8), 0, stream>>>(p);

  gemm128<0><<<dim3(128, 6), 256, 0, stream>>>(x, nullptr, wt, qb, kb, vT, nullptr, nullptr);
  attn_k<<<dim3(2, 8, 32), 256, 0, stream>>>(qb, kb, vT, ob);
  gemm128<1><<<dim3(128, 2), 256, 0, stream>>>(nullptr, ob, wt + 3 * 65536, nullptr, nullptr, nullptr, bo, out);
}